// Round 1
// baseline (6117.737 us; speedup 1.0000x reference)
//
#include <hip/hip_runtime.h>
#include <hip/hip_fp16.h>

// R6: fused producer/consumer persistent kernel.
// rocprof showed gru_fb (fallback) was what actually ran: ws < 805MB so the
// R5 two-kernel gx path never executed. This round: 256 blocks, 1/CU.
//   blocks 32..255: produce gate_x (fp16, log2e-prescaled, bias folded) into
//     a ws ring buffer (chunk = 16/32/64 timesteps picked from ws_size).
//   blocks 0..31: pure-Wh scan (384 MFMA/CU-step floor ~1862cyc), gx read as
//     6x8B u16x4 loads/lane from [t][ch][b] layout.
//   sync: per-chunk done[]/consumed[] counters, agent-scope acq/rel atomics
//     (release=wbl2, acquire=buffer_inv handles cross-XCD L2).
// ws < ~25MB -> unchanged gru_fb fallback.

typedef short v8s __attribute__((ext_vector_type(8)));   // 8 bf16
typedef float f32x4 __attribute__((ext_vector_type(4)));
typedef unsigned short u16x4 __attribute__((ext_vector_type(4)));

#define LOG2E 1.4426950408889634f

__device__ __forceinline__ unsigned short f2b(float f) {
    unsigned int u = __float_as_uint(f);
    u += 0x7FFFu + ((u >> 16) & 1u);       // RNE
    return (unsigned short)(u >> 16);
}
__device__ __forceinline__ float b2f(unsigned short h) {
    return __uint_as_float(((unsigned int)h) << 16);
}
__device__ __forceinline__ unsigned short f2h(float f) {
    union { __half h; unsigned short u; } cv;
    cv.h = __float2half_rn(f);
    return cv.u;
}
__device__ __forceinline__ float h2f(unsigned short u) {
    union { unsigned short u; __half h; } cv;
    cv.u = u;
    return __half2float(cv.h);
}
__device__ __forceinline__ v8s cvt8(f32x4 a, f32x4 b) {
    v8s r;
#pragma unroll
    for (int j = 0; j < 4; ++j) { r[j] = (short)f2b(a[j]); r[4 + j] = (short)f2b(b[j]); }
    return r;
}
__device__ __forceinline__ v8s wfrag(const float* src, float s) {
    f32x4 a = *(const f32x4*)src, b = *(const f32x4*)(src + 4);
    a *= s; b *= s;
    return cvt8(a, b);
}
__device__ __forceinline__ float rcpf(float v) {
#if __has_builtin(__builtin_amdgcn_rcpf)
    return __builtin_amdgcn_rcpf(v);
#else
    return 1.0f / v;
#endif
}
__device__ __forceinline__ float exp2f_(float v) {
#if __has_builtin(__builtin_amdgcn_exp2f)
    return __builtin_amdgcn_exp2f(v);
#else
    return __exp2f(v);
#endif
}
// sigmoid of log2e-scaled preactivation
__device__ __forceinline__ float sg(float v) { return rcpf(1.0f + exp2f_(-v)); }
// unscaled (fallback)
__device__ __forceinline__ float sigm(float v) {
    float e = __expf(-fmaxf(v, -30.0f));
    return rcpf(1.0f + e);
}
__device__ __forceinline__ float tanh_(float v) {
    float vc = fmaxf(fminf(v, 30.0f), -30.0f);
    float e = __expf(-2.0f * vc);
    return (1.0f - e) * rcpf(1.0f + e);
}
__device__ __forceinline__ f32x4 MF(v8s a, v8s b, f32x4 c) {
    return __builtin_amdgcn_mfma_f32_16x16x32_bf16(a, b, c, 0, 0, 0);
}
// A-frag order index for element (row, k): u16 units
__device__ __forceinline__ int fidx(int row, int k) {
    return ((k >> 5) << 9) + ((((k >> 3) & 3) << 4) + row) * 8 + (k & 7);
}

// ======================= fused persistent kernel =======================
// LDS: consumer: whn frags 131072 + h ping-pong 16384 = 147456
//      producer: wxf frags 98304 (fits inside same allocation)
#define S_LDS_SIZE 147456

// ctrl layout (uint): done[0..63], consumed[64..127]  (memset 1024B each launch)
extern "C" __global__ void __launch_bounds__(512, 2)
gru_fused(const float* __restrict__ x, const float* __restrict__ Wx,
          const float* __restrict__ Wh, const float* __restrict__ bias,
          const float* __restrict__ fcw, const float* __restrict__ fcb,
          unsigned short* __restrict__ gx, unsigned int* __restrict__ ctrl,
          int n_slots, int ch_shift, float* __restrict__ out)
{
    extern __shared__ char lds[];
    const int tid = threadIdx.x;
    const int w = tid >> 6, l = tid & 63;
    const int cl = l & 15, kg = l >> 4;
    const size_t slot_elems = 393216ull << ch_shift;   // 512*768 per timestep

    if (blockIdx.x >= 32) {
        // ---------------- producer: gate_x chunks into ring ----------------
        v8s* wxf = (v8s*)lds;                          // 96 frags * 64 * 16B
        const int pid = blockIdx.x - 32;               // 0..223
        const int cs4 = ch_shift - 4;

        for (int fid = w; fid < 96; fid += 8) {
            int ct = fid >> 1, k2 = fid & 1;
            float sc = (ct < 32) ? LOG2E : 2.0f * LOG2E;
            const float* src = Wx + (size_t)(ct * 16 + cl) * 64 + k2 * 32 + kg * 8;
            wxf[fid * 64 + l] = wfrag(src, sc);
        }
        const int tiles[6] = {2*w, 2*w+1, 16+2*w, 17+2*w, 32+2*w, 33+2*w};
        float bv[6];
#pragma unroll
        for (int tt = 0; tt < 6; ++tt)
            bv[tt] = bias[tiles[tt] * 16 + cl] * ((tt < 4) ? LOG2E : 2.0f * LOG2E);
        __syncthreads();

        // jobs: j = tc*32 + g, tc = 16-timestep group (0..63) -> chunk-ordered
        for (int j = pid; j < 2048; j += 224) {
            const int tc = j >> 5, g = j & 31;
            const int c = tc >> cs4;                   // chunk of this job
            const int b0 = g << 4;
            if (c >= n_slots) {                        // ring slot reuse gate
                if (tid == 0) {
                    while (__hip_atomic_load(&ctrl[64 + (c - n_slots)],
                                             __ATOMIC_ACQUIRE,
                                             __HIP_MEMORY_SCOPE_AGENT) < 32u)
                        __builtin_amdgcn_s_sleep(16);
                }
                __syncthreads();
            }
            unsigned short* gs = gx + (size_t)(c % n_slots) * slot_elems;
            const int tl0 = (tc << 4) - (c << ch_shift);   // local t of t16=0

            for (int t16 = 0; t16 < 16; ++t16) {
                const int t = (tc << 4) + t16;
                const int tl = tl0 + t16;
                const float* xs = x + ((size_t)(b0 + cl) * 1024 + t) * 64 + kg * 8;
                v8s a0 = cvt8(*(const f32x4*)xs,        *(const f32x4*)(xs + 4));
                v8s a1 = cvt8(*(const f32x4*)(xs + 32), *(const f32x4*)(xs + 36));

                f32x4 acc[6];
#pragma unroll
                for (int tt = 0; tt < 6; ++tt) {
                    acc[tt] = f32x4{0, 0, 0, 0};
                    acc[tt] = MF(a0, wxf[(tiles[tt] * 2) * 64 + l], acc[tt]);
                    acc[tt] = MF(a1, wxf[(tiles[tt] * 2 + 1) * 64 + l], acc[tt]);
                }
                // layout [tl][ch][b]: the 4 acc rows are 4 consecutive b -> u16x4
#pragma unroll
                for (int tt = 0; tt < 6; ++tt) {
                    u16x4 pk;
#pragma unroll
                    for (int i = 0; i < 4; ++i)
                        pk[i] = f2h(acc[tt][i] + bv[tt]);
                    *(u16x4*)(gs + (size_t)(tl * 768 + tiles[tt] * 16 + cl) * 512
                                 + b0 + (kg << 2)) = pk;
                }
            }
            __syncthreads();                           // drain stores (vmcnt 0)
            if (tid == 0)
                __hip_atomic_fetch_add(&ctrl[c], 1u, __ATOMIC_RELEASE,
                                       __HIP_MEMORY_SCOPE_AGENT);
        }
        return;
    }

    // ---------------- consumer: pure-Wh scan ----------------
    v8s* whn = (v8s*)lds;                              // n-gate Wh frags
    char* hl = lds + 131072;                           // h ping-pong 2*8192
    const int b0 = blockIdx.x << 4;
    const int nchunk = 1024 >> ch_shift;
    const int chs = 1 << ch_shift;
    const unsigned int jobs_pc = 32u << (ch_shift - 4);

    // n-gate Wh (tiles 32..47) -> LDS frags, scaled 2log2e
    for (int f = w; f < 128; f += 8) {
        int t5 = f >> 3, ks = f & 7;
        const float* src = Wh + (size_t)(512 + t5 * 16 + cl) * 256 + ks * 32 + kg * 8;
        whn[f * 64 + l] = wfrag(src, 2.0f * LOG2E);
    }
    // r+z Wh resident in regs, scaled log2e: 128 regs
    v8s whB[4][8];
#pragma unroll
    for (int tt = 0; tt < 4; ++tt) {
        const int tv = (tt < 2) ? (2 * w + tt) : (16 + 2 * w + (tt - 2));
        const float* src = Wh + (size_t)(tv * 16 + cl) * 256 + kg * 8;
#pragma unroll
        for (int ks = 0; ks < 8; ++ks)
            whB[tt][ks] = wfrag(src + ks * 32, LOG2E);
    }
    for (int i = tid; i < 2048; i += 512) ((unsigned int*)hl)[i] = 0u;  // h0=0
    float hprev[8] = {0, 0, 0, 0, 0, 0, 0, 0};
    const int wn0 = (2 * w) * 8, wn1 = (2 * w + 1) * 8;
    const size_t gxoff = (size_t)((w << 5) + cl) * 512 + b0 + (kg << 2);

    int t = 0;
    for (int c = 0; c < nchunk; ++c) {
        if (tid == 0) {
            while (__hip_atomic_load(&ctrl[c], __ATOMIC_ACQUIRE,
                                     __HIP_MEMORY_SCOPE_AGENT) < jobs_pc)
                __builtin_amdgcn_s_sleep(16);
        }
        // first step's __syncthreads orders the spin vs everyone's gx loads
        const unsigned short* gp = gx + (size_t)(c % n_slots) * slot_elems + gxoff;

        for (int t2 = 0; t2 < chs; ++t2, ++t) {
            __syncthreads();
            const int cur = t & 1;
            const v8s* hb = (const v8s*)(hl + cur * 8192);

            // gx: 6 x 8B vector loads, consumed ~1900cyc later
            u16x4 gv[6];
#pragma unroll
            for (int gi = 0; gi < 3; ++gi)
#pragma unroll
                for (int p = 0; p < 2; ++p)
                    gv[gi * 2 + p] = *(const u16x4*)(gp + (size_t)(gi * 256 + p * 16) * 512);
            gp += 393216;   // next t

            f32x4 aR[2] = {{0,0,0,0},{0,0,0,0}}, aZ[2] = {{0,0,0,0},{0,0,0,0}},
                  aN[2] = {{0,0,0,0},{0,0,0,0}};
#pragma unroll
            for (int ks = 0; ks < 8; ++ks) {
                v8s a  = hb[(ks << 6) + l];
                v8s n0 = whn[(wn0 + ks) * 64 + l];
                v8s n1 = whn[(wn1 + ks) * 64 + l];
                aR[0] = MF(a, whB[0][ks], aR[0]);
                aR[1] = MF(a, whB[1][ks], aR[1]);
                aZ[0] = MF(a, whB[2][ks], aZ[0]);
                aZ[1] = MF(a, whB[3][ks], aZ[1]);
                aN[0] = MF(a, n0, aN[0]);
                aN[1] = MF(a, n1, aN[1]);
            }

            unsigned short* hn = (unsigned short*)(hl + (cur ^ 1) * 8192);
#pragma unroll
            for (int p = 0; p < 2; ++p) {
                const int ch = (w << 5) + (p << 4) + cl;
                const int chbase = ((ch >> 5) << 9) + (((ch >> 3) & 3) << 7) + (ch & 7);
#pragma unroll
                for (int i = 0; i < 4; ++i) {
                    float rg = sg(aR[p][i] + h2f(gv[p][i]));
                    float zg = sg(aZ[p][i] + h2f(gv[2 + p][i]));
                    float nv = __builtin_fmaf(rg, aN[p][i], h2f(gv[4 + p][i]));
                    float ng = __builtin_fmaf(2.0f, sg(nv), -1.0f);
                    float hy = ng + zg * (hprev[p * 4 + i] - ng);
                    hprev[p * 4 + i] = hy;
                    hn[chbase + ((kg << 2) + i) * 8] = f2b(hy);
                }
            }
        }
        __syncthreads();                               // drain chunk's gx loads
        if (tid == 0)
            __hip_atomic_fetch_add(&ctrl[64 + c], 1u, __ATOMIC_RELEASE,
                                   __HIP_MEMORY_SCOPE_AGENT);
    }

    __syncthreads();
    // logits from hT (buffer 0)
    const unsigned short* hf = (const unsigned short*)hl;
    if (tid < 160) {
        int row = tid / 10, cls = tid - row * 10;
        float s = fcb[cls];
        const float* wrow = fcw + cls * 256;
        for (int k = 0; k < 256; ++k)
            s += b2f(hf[fidx(row, k)]) * wrow[k];
        out[(b0 + row) * 10 + cls] = s;
    }
}

// ================= fallback (ws too small): R3 kernel, unscaled =================
#define FB_LDS_SIZE 151552
extern "C" __global__ void __launch_bounds__(512, 2)
gru_fb(const float* __restrict__ x, const float* __restrict__ Wx,
       const float* __restrict__ Wh, const float* __restrict__ bias,
       const float* __restrict__ fcw, const float* __restrict__ fcb,
       float* __restrict__ out)
{
    extern __shared__ char lds[];
    v8s* whn = (v8s*)lds;
    char* hl = lds + 131072;
    char* xl = lds + 147456;
    const int tid = threadIdx.x;
    const int w = tid >> 6, l = tid & 63;
    const int cl = l & 15, kg = l >> 4;
    const int b0 = blockIdx.x << 4;
    const int tiles[6] = {2*w, 2*w+1, 16+2*w, 17+2*w, 32+2*w, 33+2*w};

    for (int f = w; f < 128; f += 8) {
        int t5 = f >> 3, ks = f & 7;
        const float* src = Wh + (size_t)(512 + t5*16 + cl)*256 + ks*32 + kg*8;
        whn[f*64 + l] = wfrag(src, 1.0f);
    }
    v8s whB[4][8];
#pragma unroll
    for (int tt = 0; tt < 4; ++tt) {
        const float* src = Wh + (size_t)(tiles[tt]*16 + cl)*256 + kg*8;
#pragma unroll
        for (int ks = 0; ks < 8; ++ks)
            whB[tt][ks] = wfrag(src + ks*32, 1.0f);
    }
    float brv[2], bzv[2], bhv[2];
#pragma unroll
    for (int p = 0; p < 2; ++p) {
        int ch = (w << 5) + (p << 4) + cl;
        brv[p] = bias[ch]; bzv[p] = bias[256+ch]; bhv[p] = bias[512+ch];
    }
    for (int i = tid; i < 2048; i += 512) ((unsigned int*)hl)[i] = 0u;
    const int xr = tid >> 5, xc = (tid & 31) << 1;
    const int xidx = fidx(xr, xc);
    const float* xp = x + (((size_t)(b0 + xr)) << 16) + xc;
    {
        unsigned int pk = (unsigned int)f2b(xp[0]) | ((unsigned int)f2b(xp[1]) << 16);
        *(unsigned int*)(xl + xidx*2) = pk;
    }
    xp += 64;
    const int wn0 = (2*w)*8, wn1 = (2*w+1)*8;

    for (int t = 0; t < 1024; ++t) {
        __syncthreads();
        const int cur = t & 1;
        const v8s* hb = (const v8s*)(hl + cur*8192);
        const v8s* xb = (const v8s*)(xl + cur*2048);
        float xv0 = 0.0f, xv1 = 0.0f;
        if (t < 1023) { xv0 = xp[0]; xv1 = xp[1]; xp += 64; }
        v8s wxr[12];
#pragma unroll
        for (int tt = 0; tt < 6; ++tt) {
            const float* s0 = Wx + (size_t)(tiles[tt]*16 + cl)*64 + kg*8;
            wxr[tt*2]   = wfrag(s0, 1.0f);
            wxr[tt*2+1] = wfrag(s0 + 32, 1.0f);
        }
        f32x4 acc[8];
#pragma unroll
        for (int i = 0; i < 8; ++i) acc[i] = f32x4{0,0,0,0};
#pragma unroll
        for (int ks = 0; ks < 8; ++ks) {
            v8s a = hb[(ks << 6) + l];
            v8s n0 = whn[(wn0 + ks)*64 + l];
            v8s n1 = whn[(wn1 + ks)*64 + l];
            acc[0] = MF(a, whB[0][ks], acc[0]);
            acc[1] = MF(a, whB[1][ks], acc[1]);
            acc[2] = MF(a, whB[2][ks], acc[2]);
            acc[3] = MF(a, whB[3][ks], acc[3]);
            acc[4] = MF(a, n0, acc[4]);
            acc[5] = MF(a, n1, acc[5]);
        }
#pragma unroll
        for (int k2 = 0; k2 < 2; ++k2) {
            v8s ax = xb[(k2 << 6) + l];
            acc[0] = MF(ax, wxr[0+k2], acc[0]);
            acc[1] = MF(ax, wxr[2+k2], acc[1]);
            acc[2] = MF(ax, wxr[4+k2], acc[2]);
            acc[3] = MF(ax, wxr[6+k2], acc[3]);
            acc[6] = MF(ax, wxr[8+k2], acc[6]);
            acc[7] = MF(ax, wxr[10+k2], acc[7]);
        }
        const unsigned short* hc16 = (const unsigned short*)hb;
        unsigned short* hn16 = (unsigned short*)(hl + ((cur ^ 1) * 8192));
#pragma unroll
        for (int p = 0; p < 2; ++p) {
            int ch = (w << 5) + (p << 4) + cl;
            int chbase = ((ch >> 5) << 9) + (((ch >> 3) & 3) << 7) + (ch & 7);
#pragma unroll
            for (int i = 0; i < 4; ++i) {
                int row = (kg << 2) + i;
                int idx = chbase + (row << 3);
                float rg = sigm(acc[p][i] + brv[p]);
                float zg = sigm(acc[2+p][i] + bzv[p]);
                float ng = tanh_(acc[6+p][i] + bhv[p] + rg * acc[4+p][i]);
                float hold = b2f(hc16[idx]);
                float hy = ng + zg * (hold - ng);
                hn16[idx] = f2b(hy);
            }
        }
        if (t < 1023) {
            unsigned int pk = (unsigned int)f2b(xv0) | ((unsigned int)f2b(xv1) << 16);
            *(unsigned int*)(xl + ((cur ^ 1) * 2048) + xidx*2) = pk;
        }
    }
    __syncthreads();
    const unsigned short* hf = (const unsigned short*)hl;
    if (tid < 160) {
        int row = tid / 10, cls = tid - row * 10;
        float s = fcb[cls];
        const float* wrow = fcw + cls * 256;
        for (int k = 0; k < 256; ++k)
            s += b2f(hf[fidx(row, k)]) * wrow[k];
        out[(b0 + row)*10 + cls] = s;
    }
}

extern "C" void kernel_launch(void* const* d_in, const int* in_sizes, int n_in,
                              void* d_out, int out_size, void* d_ws, size_t ws_size,
                              hipStream_t stream) {
    const float* x    = (const float*)d_in[0];
    const float* Wx   = (const float*)d_in[1];
    const float* Wh   = (const float*)d_in[2];
    const float* bias = (const float*)d_in[3];
    const float* fcw  = (const float*)d_in[4];
    const float* fcb  = (const float*)d_in[5];

    // pick largest chunk (64/32/16 timesteps) with >=2 ring slots in ws
    int ch_shift = -1, n_slots = 0;
    for (int cs = 6; cs >= 4; --cs) {
        unsigned long long slot = 786432ull << cs;     // bytes per slot
        if (ws_size < 1024ull + 2ull * slot) continue;
        int nch = 1024 >> cs;
        unsigned long long n = (ws_size - 1024ull) / slot;
        n_slots = (n > (unsigned long long)nch) ? nch : (int)n;
        ch_shift = cs;
        break;
    }

    if (ch_shift >= 4) {
        unsigned int* ctrl =
            (unsigned int*)((char*)d_ws + (786432ull << ch_shift) * (size_t)n_slots);
        (void)hipMemsetAsync(ctrl, 0, 1024, stream);
        (void)hipFuncSetAttribute((const void*)gru_fused,
                                  hipFuncAttributeMaxDynamicSharedMemorySize, S_LDS_SIZE);
        gru_fused<<<dim3(256), dim3(512), S_LDS_SIZE, stream>>>(
            x, Wx, Wh, bias, fcw, fcb,
            (unsigned short*)d_ws, ctrl, n_slots, ch_shift, (float*)d_out);
    } else {
        (void)hipFuncSetAttribute((const void*)gru_fb,
                                  hipFuncAttributeMaxDynamicSharedMemorySize, FB_LDS_SIZE);
        gru_fb<<<dim3(32), dim3(512), FB_LDS_SIZE, stream>>>(
            x, Wx, Wh, bias, fcw, fcb, (float*)d_out);
    }
}

// Round 2
// 1966.689 us; speedup vs baseline: 3.1107x; 3.1107x over previous
//
#include <hip/hip_runtime.h>

// R7: single persistent scan kernel, no workspace, no producer/consumer.
// Post-mortem of R6: gx round-trip via ws was latency-bound (uncoalesced
// 1KB-stride 8B accesses, same-step load->use, cross-XCD line sharing) ->
// 6026us. The fallback (1905us) was VALU-bound rebuilding Wx frags every
// step. Fix: Wx frags are only 12 v8s/wave (48 VGPR) -> hoist them out of
// the time loop (register/AGPR resident), fuse Wx MFMA into the scan
// (+12 MFMA/wave-step), and apply the HW-validated log2e prescale so the
// epilogue is pure exp2/rcp. Bias folded into accumulator init.
// Per-step/wave: 60 MFMA + 26 ds_read_b128 + ~90 VALU epilogue. Zero
// per-step global traffic except the 8B x-prefetch.

typedef short v8s __attribute__((ext_vector_type(8)));   // 8 bf16
typedef float f32x4 __attribute__((ext_vector_type(4)));

#define LOG2E 1.4426950408889634f

__device__ __forceinline__ unsigned short f2b(float f) {
    unsigned int u = __float_as_uint(f);
    u += 0x7FFFu + ((u >> 16) & 1u);       // RNE
    return (unsigned short)(u >> 16);
}
__device__ __forceinline__ float b2f(unsigned short h) {
    return __uint_as_float(((unsigned int)h) << 16);
}
__device__ __forceinline__ v8s cvt8(f32x4 a, f32x4 b) {
    v8s r;
#pragma unroll
    for (int j = 0; j < 4; ++j) { r[j] = (short)f2b(a[j]); r[4 + j] = (short)f2b(b[j]); }
    return r;
}
__device__ __forceinline__ v8s wfrag(const float* src, float s) {
    f32x4 a = *(const f32x4*)src, b = *(const f32x4*)(src + 4);
    a *= s; b *= s;
    return cvt8(a, b);
}
__device__ __forceinline__ float rcpf(float v) {
#if __has_builtin(__builtin_amdgcn_rcpf)
    return __builtin_amdgcn_rcpf(v);
#else
    return 1.0f / v;
#endif
}
__device__ __forceinline__ float exp2f_(float v) {
#if __has_builtin(__builtin_amdgcn_exp2f)
    return __builtin_amdgcn_exp2f(v);
#else
    return __exp2f(v);
#endif
}
// sigmoid of log2e-prescaled preactivation (HW-validated in R6 consumer)
__device__ __forceinline__ float sg(float v) { return rcpf(1.0f + exp2f_(-v)); }
__device__ __forceinline__ f32x4 MF(v8s a, v8s b, f32x4 c) {
    return __builtin_amdgcn_mfma_f32_16x16x32_bf16(a, b, c, 0, 0, 0);
}
// A-frag order index for element (row, k): u16 units
__device__ __forceinline__ int fidx(int row, int k) {
    return ((k >> 5) << 9) + ((((k >> 3) & 3) << 4) + row) * 8 + (k & 7);
}

// LDS: whn frags 131072 | h ping-pong 2*8192 | x ping-pong 2*2048
#define LDS_H    131072
#define LDS_X    147456
#define LDS_SIZE 151552

extern "C" __global__ void __launch_bounds__(512, 2)
gru_v7(const float* __restrict__ x, const float* __restrict__ Wx,
       const float* __restrict__ Wh, const float* __restrict__ bias,
       const float* __restrict__ fcw, const float* __restrict__ fcb,
       float* __restrict__ out)
{
    extern __shared__ char lds[];
    v8s* whn = (v8s*)lds;                  // n-gate Wh frags (16 tiles x 8 ks)
    char* hl = lds + LDS_H;
    char* xl = lds + LDS_X;

    const int tid = threadIdx.x;
    const int w = tid >> 6, l = tid & 63;
    const int cl = l & 15, kg = l >> 4;
    const int b0 = blockIdx.x << 4;
    const int tiles[6] = {2*w, 2*w+1, 16+2*w, 17+2*w, 32+2*w, 33+2*w};

    // n-gate Wh (rows 512..767) -> LDS frags, scaled 2*log2e
    for (int f = w; f < 128; f += 8) {
        int t5 = f >> 3, ks = f & 7;
        const float* src = Wh + (size_t)(512 + t5*16 + cl)*256 + ks*32 + kg*8;
        whn[f*64 + l] = wfrag(src, 2.0f*LOG2E);
    }
    // r,z Wh tiles register-resident, scaled log2e (128 regs)
    v8s whB[4][8];
#pragma unroll
    for (int tt = 0; tt < 4; ++tt) {
        const float* src = Wh + (size_t)(tiles[tt]*16 + cl)*256 + kg*8;
#pragma unroll
        for (int ks = 0; ks < 8; ++ks)
            whB[tt][ks] = wfrag(src + ks*32, LOG2E);
    }
    // Wx frags HOISTED: 6 tiles x 2 k-slices, prescaled (48 regs)
    v8s wxr[12];
#pragma unroll
    for (int tt = 0; tt < 6; ++tt) {
        const float sc = (tt < 4) ? LOG2E : 2.0f*LOG2E;
        const float* s0 = Wx + (size_t)(tiles[tt]*16 + cl)*64 + kg*8;
        wxr[tt*2]   = wfrag(s0, sc);
        wxr[tt*2+1] = wfrag(s0 + 32, sc);
    }
    // prescaled bias (folded into acc init each step)
    float brv[2], bzv[2], bhv[2];
#pragma unroll
    for (int p = 0; p < 2; ++p) {
        int ch = (w << 5) + (p << 4) + cl;
        brv[p] = bias[ch] * LOG2E;
        bzv[p] = bias[256 + ch] * LOG2E;
        bhv[p] = bias[512 + ch] * 2.0f*LOG2E;
    }

    // h0 = 0 (buffer 0) + register copy of own channels
    for (int i = tid; i < 2048; i += 512) ((unsigned int*)hl)[i] = 0u;
    float hprev[8] = {0, 0, 0, 0, 0, 0, 0, 0};

    // x staging: t=0 into buffer 0
    const int xr = tid >> 5, xc = (tid & 31) << 1;
    const int xidx = fidx(xr, xc);
    const float* xp = x + (((size_t)(b0 + xr)) << 16) + xc;
    {
        unsigned int pk = (unsigned int)f2b(xp[0]) | ((unsigned int)f2b(xp[1]) << 16);
        *(unsigned int*)(xl + xidx*2) = pk;
    }
    xp += 64;
    const int wn0 = (2*w)*8, wn1 = (2*w+1)*8;

    for (int t = 0; t < 1024; ++t) {
        __syncthreads();
        const int cur = t & 1;
        const v8s* hb = (const v8s*)(hl + cur*8192);
        const v8s* xb = (const v8s*)(xl + cur*2048);

        // prefetch next timestep's x slice (8B/lane, consumed at step end)
        float xv0 = 0.0f, xv1 = 0.0f;
        if (t < 1023) { xv0 = xp[0]; xv1 = xp[1]; xp += 64; }

        // acc init = prescaled bias (r,z,n-x); n-h starts at 0
        f32x4 acc[8];
        acc[0] = f32x4{brv[0], brv[0], brv[0], brv[0]};
        acc[1] = f32x4{brv[1], brv[1], brv[1], brv[1]};
        acc[2] = f32x4{bzv[0], bzv[0], bzv[0], bzv[0]};
        acc[3] = f32x4{bzv[1], bzv[1], bzv[1], bzv[1]};
        acc[4] = f32x4{0, 0, 0, 0};
        acc[5] = f32x4{0, 0, 0, 0};
        acc[6] = f32x4{bhv[0], bhv[0], bhv[0], bhv[0]};
        acc[7] = f32x4{bhv[1], bhv[1], bhv[1], bhv[1]};

#pragma unroll
        for (int ks = 0; ks < 8; ++ks) {
            v8s a  = hb[(ks << 6) + l];
            v8s n0 = whn[(wn0 + ks)*64 + l];
            v8s n1 = whn[(wn1 + ks)*64 + l];
            acc[0] = MF(a, whB[0][ks], acc[0]);
            acc[1] = MF(a, whB[1][ks], acc[1]);
            acc[2] = MF(a, whB[2][ks], acc[2]);
            acc[3] = MF(a, whB[3][ks], acc[3]);
            acc[4] = MF(a, n0, acc[4]);
            acc[5] = MF(a, n1, acc[5]);
        }
#pragma unroll
        for (int k2 = 0; k2 < 2; ++k2) {
            v8s ax = xb[(k2 << 6) + l];
            acc[0] = MF(ax, wxr[0  + k2], acc[0]);
            acc[1] = MF(ax, wxr[2  + k2], acc[1]);
            acc[2] = MF(ax, wxr[4  + k2], acc[2]);
            acc[3] = MF(ax, wxr[6  + k2], acc[3]);
            acc[6] = MF(ax, wxr[8  + k2], acc[6]);
            acc[7] = MF(ax, wxr[10 + k2], acc[7]);
        }

        unsigned short* hn = (unsigned short*)(hl + (cur ^ 1) * 8192);
#pragma unroll
        for (int p = 0; p < 2; ++p) {
            const int ch = (w << 5) + (p << 4) + cl;
            const int chbase = ((ch >> 5) << 9) + (((ch >> 3) & 3) << 7) + (ch & 7);
#pragma unroll
            for (int i = 0; i < 4; ++i) {
                float rg = sg(acc[p][i]);
                float zg = sg(acc[2 + p][i]);
                float nv = __builtin_fmaf(rg, acc[4 + p][i], acc[6 + p][i]);
                float ng = __builtin_fmaf(2.0f, sg(nv), -1.0f);
                float hy = ng + zg * (hprev[p*4 + i] - ng);
                hprev[p*4 + i] = hy;
                hn[chbase + ((kg << 2) + i) * 8] = f2b(hy);
            }
        }
        // stage next x into other buffer
        if (t < 1023) {
            unsigned int pk = (unsigned int)f2b(xv0) | ((unsigned int)f2b(xv1) << 16);
            *(unsigned int*)(xl + ((cur ^ 1) * 2048) + xidx*2) = pk;
        }
    }

    __syncthreads();
    // logits from hT (buffer 0 after 1024 steps)
    const unsigned short* hf = (const unsigned short*)hl;
    if (tid < 160) {
        int row = tid / 10, cls = tid - row * 10;
        float s = fcb[cls];
        const float* wrow = fcw + cls * 256;
        for (int k = 0; k < 256; ++k)
            s += b2f(hf[fidx(row, k)]) * wrow[k];
        out[(b0 + row)*10 + cls] = s;
    }
}

extern "C" void kernel_launch(void* const* d_in, const int* in_sizes, int n_in,
                              void* d_out, int out_size, void* d_ws, size_t ws_size,
                              hipStream_t stream) {
    const float* x    = (const float*)d_in[0];
    const float* Wx   = (const float*)d_in[1];
    const float* Wh   = (const float*)d_in[2];
    const float* bias = (const float*)d_in[3];
    const float* fcw  = (const float*)d_in[4];
    const float* fcb  = (const float*)d_in[5];
    (void)d_ws; (void)ws_size;

    (void)hipFuncSetAttribute((const void*)gru_v7,
                              hipFuncAttributeMaxDynamicSharedMemorySize, LDS_SIZE);
    gru_v7<<<dim3(32), dim3(512), LDS_SIZE, stream>>>(
        x, Wx, Wh, bias, fcw, fcb, (float*)d_out);
}